// Round 3
// baseline (195.116 us; speedup 1.0000x reference)
//
#include <hip/hip_runtime.h>
#include <stdint.h>

#define NS 64     // N_msa (s)
#define NT 384    // N_tok (i, j)
#define CM 64     // c_m
#define CH 32     // c_h
#define CZ 128    // c_z

typedef __attribute__((ext_vector_type(8))) short bf16x8;
typedef __attribute__((ext_vector_type(16))) float f32x16;
typedef __attribute__((ext_vector_type(4))) float f32x4;
typedef __attribute__((ext_vector_type(4))) uint32_t u32x4;

#define MFMA __builtin_amdgcn_mfma_f32_32x32x16_bf16

// round-to-nearest-even f32 -> bf16 bits
static __device__ __forceinline__ uint16_t f2bf(float f) {
  uint32_t u = __float_as_uint(f);
  u = (u + 0x7FFFu + ((u >> 16) & 1u)) >> 16;
  return (uint16_t)u;
}
static __device__ __forceinline__ uint32_t pack2(float lo, float hi) {
  return (uint32_t)f2bf(lo) | ((uint32_t)f2bf(hi) << 16);
}
// O2 swizzle: O2[pair][kl] bf16, byte = pair*256 + kl*2.
// Writes spread via pair bits 11-13; reads via pair bits 8-10. <=2-way residual (free).
static __device__ __forceinline__ int swzO(int x) {
  return x ^ ((((x >> 8) ^ (x >> 11)) & 7) << 4);
}

// ---- merged prep: LN+proj -> AF2/BF; w_out -> W2 frag-major; inv_norm ------
// AF2: GEMM1 B-operand, slab-major: rb = (c>>2)*48 + (i>>3), r = (i&7)*4 + (c&3)
//   AF2[((rb*4+kk)*64 + lane)*8 + e] = a[s=kk*16+(lane>>5)*8+e][i][c], lane&31 = r
// BF : BF[((j*4+kk)*64 + lane)*8 + e] = b[s][j][d=lane&31]
// W2 : W2[((kk*4+zt)*64 + lane)*8 + e] = w_out[z=zt*32+(lane&31)][K=kk*16+(lane>>5)*8+e]
__global__ __launch_bounds__(256) void k_pre(
    const float* __restrict__ m, const float* __restrict__ mask,
    const float* __restrict__ lnw, const float* __restrict__ lnb,
    const float* __restrict__ w1, const float* __restrict__ w2,
    const float* __restrict__ wout,
    uint16_t* __restrict__ AF2, uint16_t* __restrict__ BF,
    uint16_t* __restrict__ W2, float* __restrict__ invn) {
  __shared__ float4 wsh4[2][1024];   // w1, w2 as float4 (32 KB)
  __shared__ float4 mn4[64 * 17];    // LN result, row pitch 17 float4 (68 f) = conflict-free
  const int b = blockIdx.x;
  const int tid = threadIdx.x;
  if (b < NT) {
    const int i = b;
    const int wv = tid >> 6, lane = tid & 63;
    for (int t = tid; t < 1024; t += 256) {
      wsh4[0][t] = ((const float4*)w1)[t];
      wsh4[1][t] = ((const float4*)w2)[t];
    }
    const float lw = lnw[lane], lb = lnb[lane];
    float* mnf = (float*)mn4;
    for (int s = wv; s < NS; s += 4) {
      float x = m[(s * NT + i) * CM + lane];
      float sum = x, sq = x * x;
#pragma unroll
      for (int off = 32; off; off >>= 1) {
        sum += __shfl_xor(sum, off);
        sq += __shfl_xor(sq, off);
      }
      float mu = sum * (1.f / 64.f);
      float var = sq * (1.f / 64.f) - mu * mu;
      float rs = 1.f / sqrtf(var + 1e-5f);
      mnf[s * 68 + lane] = (x - mu) * rs * lw + lb;
    }
    __syncthreads();
    const int s = lane;
    const int cb = tid >> 6;  // c = cb*8 + k
    float accA[8] = {0, 0, 0, 0, 0, 0, 0, 0};
    float accB[8] = {0, 0, 0, 0, 0, 0, 0, 0};
#pragma unroll
    for (int q = 0; q < 16; ++q) {
      float4 v = mn4[s * 17 + q];
#pragma unroll
      for (int k = 0; k < 8; ++k) {
        float4 wa = wsh4[0][(cb * 8 + k) * 16 + q];
        float4 wb = wsh4[1][(cb * 8 + k) * 16 + q];
        accA[k] = fmaf(v.x, wa.x, fmaf(v.y, wa.y, fmaf(v.z, wa.z, fmaf(v.w, wa.w, accA[k]))));
        accB[k] = fmaf(v.x, wb.x, fmaf(v.y, wb.y, fmaf(v.z, wb.z, fmaf(v.w, wb.w, accB[k]))));
      }
    }
    const float msk = mask[s * NT + i];
    const int kkq = s >> 4, hh = (s >> 3) & 1, e = s & 7;
    const size_t baseB = ((size_t)(i * 4 + kkq) * 64 + hh * 32) * 8 + e;
#pragma unroll
    for (int k = 0; k < 8; ++k) {
      int c = cb * 8 + k;
      BF[baseB + (size_t)c * 8] = f2bf(accB[k] * msk);
      int rb = (c >> 2) * 48 + (i >> 3);
      int r = (i & 7) * 4 + (c & 3);
      AF2[((size_t)(rb * 4 + kkq) * 64 + hh * 32 + r) * 8 + e] = f2bf(accA[k] * msk);
    }
  } else if (b < NT + 64) {
    const int g = (b - NT) * 256 + tid;  // 0..16383
    const int l = g & 63, zt = (g >> 6) & 3, kk = g >> 8;
    const float* src = wout + (zt * 32 + (l & 31)) * 1024 + kk * 16 + (l >> 5) * 8;
    uint16_t* dst = W2 + (size_t)g * 8;
#pragma unroll
    for (int e2 = 0; e2 < 8; ++e2) dst[e2] = f2bf(src[e2]);
  } else {
    const int t = (b - NT - 64) * 256 + tid;  // 0..147455
    const int i = t / NT, j = t - i * NT;
    float acc = 0.f;
#pragma unroll 8
    for (int s2 = 0; s2 < NS; ++s2) acc += mask[s2 * NT + i] * mask[s2 * NT + j];
    invn[t] = 1.f / (acc + 1e-3f);
  }
}

// ---- main: per block 16x8 (i,j) pairs, 8 c-slabs of K=128, fused GEMM1+GEMM2
// LDS: [0,32K) O2[0]; [32K,64K) O2[1]; [64K,96K) Wb[0]; [96K,128K) Wb[1]
// waves: GEMM1 wave=jt (j0+jt, all 16 i); GEMM2 wave=(kh, mp, zp), 2x2 tiles, K-split
__global__ __launch_bounds__(512, 2) void k_main(
    const uint16_t* __restrict__ AF2, const uint16_t* __restrict__ BF,
    const uint16_t* __restrict__ W2, const float* __restrict__ b_out,
    const float* __restrict__ invn, float* __restrict__ out) {
  extern __shared__ char lds[];
  const int tid = threadIdx.x;
  const int wv = tid >> 6, l = tid & 63;
  const int lo5 = l & 31, hi = l >> 5;
  const int i0 = blockIdx.x * 16, j0 = blockIdx.y * 8;
  const int ib0 = blockIdx.x * 2;
  const int jt = wv;                                // GEMM1 role
  const int kh = wv >> 2, mp = (wv >> 1) & 1, zp = wv & 1;  // GEMM2 role

  // preload BF fragments (b doesn't depend on c -> reused all 8 slabs)
  bf16x8 bfr[4];
  {
    const uint16_t* p = BF + (size_t)(j0 + jt) * 4 * 512 + (size_t)l * 8;
#pragma unroll
    for (int kk = 0; kk < 4; ++kk) bfr[kk] = *(const bf16x8*)(p + kk * 512);
  }

  f32x16 acc2[2][2];
#pragma unroll
  for (int mi = 0; mi < 2; ++mi)
#pragma unroll
    for (int zi = 0; zi < 2; ++zi) acc2[mi][zi] = (f32x16){};

  for (int cbk = 0; cbk < 8; ++cbk) {
    const int cur = cbk & 1;
    char* ldsO = lds + cur * 32768;
    char* ldsW = lds + 65536 + cur * 32768;

    // T14: issue W-slab stage loads early (land after GEMM1 under MFMA)
    u32x4 wst[4];
    {
      const uint32_t* src = (const uint32_t*)(W2 + (size_t)cbk * 16384);
#pragma unroll
      for (int it = 0; it < 4; ++it) wst[it] = *(const u32x4*)(src + it * 2048 + tid * 4);
    }

    // ---- GEMM1: O-slab[128 pairs][128 kl], A = BF(jt) rows d, B = AF2 rows (i,c)
    f32x16 acc1[2];
    acc1[0] = (f32x16){};
    acc1[1] = (f32x16){};
    {
      const uint16_t* Ap = AF2 + (size_t)(cbk * 48 + ib0) * 4 * 512 + (size_t)l * 8;
#pragma unroll
      for (int kk = 0; kk < 4; ++kk) {
        bf16x8 a0 = *(const bf16x8*)(Ap + kk * 512);
        bf16x8 a1 = *(const bf16x8*)(Ap + (4 + kk) * 512);
        acc1[0] = MFMA(bfr[kk], a0, acc1[0], 0, 0, 0);
        acc1[1] = MFMA(bfr[kk], a1, acc1[1], 0, 0, 0);
      }
    }
    // write staged W-slab (linear, conflict-free)
#pragma unroll
    for (int it = 0; it < 4; ++it) *(u32x4*)(ldsW + it * 8192 + tid * 16) = wst[it];
    // write O-slab: lane col = (i,c): pair = (h*8 + (lo5>>2))*8 + jt, kl = (lo5&3)*32 + d
#pragma unroll
    for (int h = 0; h < 2; ++h) {
      const int p = (h * 8 + (lo5 >> 2)) * 8 + jt;
      const int base = p * 256 + (lo5 & 3) * 64 + hi * 8;
#pragma unroll
      for (int g = 0; g < 4; ++g) {
        uint64_t v = (uint64_t)pack2(acc1[h][4 * g + 0], acc1[h][4 * g + 1]) |
                     ((uint64_t)pack2(acc1[h][4 * g + 2], acc1[h][4 * g + 3]) << 32);
        *(uint64_t*)(ldsO + swzO(base + g * 16)) = v;
      }
    }
    __syncthreads();  // one barrier per slab (dbuf makes the second unnecessary)

    // ---- GEMM2: acc2 += O-slab x W-slab; wave = (kh, mp, zp), 2x2 register blocking
#pragma unroll
    for (int kx = 0; kx < 4; ++kx) {
      const int kkl = kh * 4 + kx;
      bf16x8 of[2], wf[2];
#pragma unroll
      for (int mi = 0; mi < 2; ++mi) {
        const int mt = mp * 2 + mi;
        of[mi] = *(const bf16x8*)(ldsO + swzO((mt * 32 + lo5) * 256 + kkl * 32 + hi * 16));
      }
#pragma unroll
      for (int zi = 0; zi < 2; ++zi) {
        const int zt = zp * 2 + zi;
        wf[zi] = *(const bf16x8*)(ldsW + (kkl * 4 + zt) * 1024 + l * 16);
      }
#pragma unroll
      for (int mi = 0; mi < 2; ++mi)
#pragma unroll
        for (int zi = 0; zi < 2; ++zi)
          acc2[mi][zi] = MFMA(of[mi], wf[zi], acc2[mi][zi], 0, 0, 0);
    }
    // next iteration writes the other buffers -> no second barrier needed
  }

  // ---- K-split reduce: kh=1 -> scratch in dead buffers (O2[0], Wb[0])
  const int sidx = mp * 2 + zp;
  const int wbase = (sidx < 2) ? sidx * 16384 : 65536 + (sidx - 2) * 16384;
  if (kh == 1) {
#pragma unroll
    for (int mi = 0; mi < 2; ++mi)
#pragma unroll
      for (int zi = 0; zi < 2; ++zi)
#pragma unroll
        for (int g = 0; g < 4; ++g) {
          f32x4 v = {acc2[mi][zi][4 * g + 0], acc2[mi][zi][4 * g + 1],
                     acc2[mi][zi][4 * g + 2], acc2[mi][zi][4 * g + 3]};
          *(f32x4*)(lds + wbase + ((mi * 2 + zi) * 4 + g) * 1024 + l * 16) = v;
        }
  }
  __syncthreads();
  if (kh == 0) {
#pragma unroll
    for (int mi = 0; mi < 2; ++mi)
#pragma unroll
      for (int zi = 0; zi < 2; ++zi)
#pragma unroll
        for (int g = 0; g < 4; ++g) {
          f32x4 v = *(const f32x4*)(lds + wbase + ((mi * 2 + zi) * 4 + g) * 1024 + l * 16);
#pragma unroll
          for (int jj = 0; jj < 4; ++jj) acc2[mi][zi][4 * g + jj] += v[jj];
        }
  }
  // stage invn for this block's 128 pairs into dead Wb[1]
  if (tid < 128)
    ((float*)(lds + 98304))[tid] = invn[(size_t)(i0 + (tid >> 3)) * NT + j0 + (tid & 7)];
  __syncthreads();
  if (kh == 0) {
    const float bo0 = b_out[(zp * 2) * 32 + lo5];
    const float bo1 = b_out[(zp * 2 + 1) * 32 + lo5];
    const float* invl = (const float*)(lds + 98304);
#pragma unroll
    for (int mi = 0; mi < 2; ++mi) {
      const int mt = mp * 2 + mi;
#pragma unroll
      for (int e = 0; e < 16; ++e) {
        const int row = mt * 32 + (e & 3) + 8 * (e >> 2) + 4 * hi;  // pair = i16*8 + j
        const float inv = invl[row];
        const size_t n = (size_t)(i0 + (row >> 3)) * NT + j0 + (row & 7);
        out[n * CZ + zp * 64 + lo5] = (acc2[mi][0][e] + bo0) * inv;
        out[n * CZ + zp * 64 + 32 + lo5] = (acc2[mi][1][e] + bo1) * inv;
      }
    }
  }
}

extern "C" void kernel_launch(void* const* d_in, const int* in_sizes, int n_in,
                              void* d_out, int out_size, void* d_ws, size_t ws_size,
                              hipStream_t stream) {
  const float* m    = (const float*)d_in[0];
  const float* mask = (const float*)d_in[1];
  const float* lnw  = (const float*)d_in[2];
  const float* lnb  = (const float*)d_in[3];
  const float* w1   = (const float*)d_in[4];
  const float* w2   = (const float*)d_in[5];
  const float* wout = (const float*)d_in[6];
  const float* bout = (const float*)d_in[7];
  float* out = (float*)d_out;

  char* ws = (char*)d_ws;
  uint16_t* AF2 = (uint16_t*)ws;                        // 1.5 MB
  uint16_t* BF  = (uint16_t*)(ws + 1572864);            // 1.5 MB
  uint16_t* W2  = (uint16_t*)(ws + 3145728);            // 256 KB
  float* invn   = (float*)(ws + 3407872);               // 576 KB

  k_pre<<<1024, 256, 0, stream>>>(m, mask, lnw, lnb, w1, w2, wout, AF2, BF, W2, invn);

  (void)hipFuncSetAttribute(reinterpret_cast<const void*>(k_main),
                            hipFuncAttributeMaxDynamicSharedMemorySize, 131072);
  k_main<<<dim3(NT / 16, NT / 8), 512, 131072, stream>>>(AF2, BF, W2, bout, invn, out);
}

// Round 5
// 174.453 us; speedup vs baseline: 1.1184x; 1.1184x over previous
//
#include <hip/hip_runtime.h>
#include <stdint.h>

#define NS 64     // N_msa (s)
#define NT 384    // N_tok (i, j)
#define CM 64     // c_m
#define CH 32     // c_h
#define CZ 128    // c_z

typedef __attribute__((ext_vector_type(8))) short bf16x8;
typedef __attribute__((ext_vector_type(16))) float f32x16;

#define MFMA __builtin_amdgcn_mfma_f32_32x32x16_bf16

// round-to-nearest-even f32 -> bf16 bits
static __device__ __forceinline__ uint16_t f2bf(float f) {
  uint32_t u = __float_as_uint(f);
  u = (u + 0x7FFFu + ((u >> 16) & 1u)) >> 16;
  return (uint16_t)u;
}
static __device__ __forceinline__ uint32_t pack2(float lo, float hi) {
  return (uint32_t)f2bf(lo) | ((uint32_t)f2bf(hi) << 16);
}
// O-slab swizzle (offset within 16 KB buffer, byte = pair*256 + kl*2):
// bank bits 4..6 ^= (pair&7) ^ (pair>>3). Involution; 16B-granule-preserving.
static __device__ __forceinline__ int swzO(int x) {
  return x ^ ((((x >> 8) ^ (x >> 11)) & 7) << 4);
}

// ---- merged prep: LN+proj -> AF2/BF; w_out -> W2 frag-major; inv_norm ------
// AF2: GEMM1 B-operand, slab-major: rb = (c>>2)*48 + (i>>3), r = (i&7)*4 + (c&3)
//   AF2[((rb*4+kk)*64 + lane)*8 + e] = a[s=kk*16+(lane>>5)*8+e][i][c], lane&31 = r
// BF : BF[((j*4+kk)*64 + lane)*8 + e] = b[s][j][d=lane&31]
// W2 : W2[((kk*4+zt)*64 + lane)*8 + e] = w_out[z=zt*32+(lane&31)][K=kk*16+(lane>>5)*8+e]
__global__ __launch_bounds__(256) void k_pre(
    const float* __restrict__ m, const float* __restrict__ mask,
    const float* __restrict__ lnw, const float* __restrict__ lnb,
    const float* __restrict__ w1, const float* __restrict__ w2,
    const float* __restrict__ wout,
    uint16_t* __restrict__ AF2, uint16_t* __restrict__ BF,
    uint16_t* __restrict__ W2, float* __restrict__ invn) {
  __shared__ float4 wsh4[2][1024];   // w1, w2 as float4 (32 KB)
  __shared__ float4 mn4[64 * 17];    // LN result, row pitch 17 float4 (68 f) = conflict-free
  const int b = blockIdx.x;
  const int tid = threadIdx.x;
  if (b < NT) {
    const int i = b;
    const int wv = tid >> 6, lane = tid & 63;
    for (int t = tid; t < 1024; t += 256) {
      wsh4[0][t] = ((const float4*)w1)[t];
      wsh4[1][t] = ((const float4*)w2)[t];
    }
    const float lw = lnw[lane], lb = lnb[lane];
    float* mnf = (float*)mn4;
    for (int s = wv; s < NS; s += 4) {
      float x = m[(s * NT + i) * CM + lane];
      float sum = x, sq = x * x;
#pragma unroll
      for (int off = 32; off; off >>= 1) {
        sum += __shfl_xor(sum, off);
        sq += __shfl_xor(sq, off);
      }
      float mu = sum * (1.f / 64.f);
      float var = sq * (1.f / 64.f) - mu * mu;
      float rs = 1.f / sqrtf(var + 1e-5f);
      mnf[s * 68 + lane] = (x - mu) * rs * lw + lb;
    }
    __syncthreads();
    const int s = lane;
    const int cb = tid >> 6;  // c = cb*8 + k
    float accA[8] = {0, 0, 0, 0, 0, 0, 0, 0};
    float accB[8] = {0, 0, 0, 0, 0, 0, 0, 0};
#pragma unroll
    for (int q = 0; q < 16; ++q) {
      float4 v = mn4[s * 17 + q];
#pragma unroll
      for (int k = 0; k < 8; ++k) {
        float4 wa = wsh4[0][(cb * 8 + k) * 16 + q];
        float4 wb = wsh4[1][(cb * 8 + k) * 16 + q];
        accA[k] = fmaf(v.x, wa.x, fmaf(v.y, wa.y, fmaf(v.z, wa.z, fmaf(v.w, wa.w, accA[k]))));
        accB[k] = fmaf(v.x, wb.x, fmaf(v.y, wb.y, fmaf(v.z, wb.z, fmaf(v.w, wb.w, accB[k]))));
      }
    }
    const float msk = mask[s * NT + i];
    const int kkq = s >> 4, hh = (s >> 3) & 1, e = s & 7;
    const size_t baseB = ((size_t)(i * 4 + kkq) * 64 + hh * 32) * 8 + e;
#pragma unroll
    for (int k = 0; k < 8; ++k) {
      int c = cb * 8 + k;
      BF[baseB + (size_t)c * 8] = f2bf(accB[k] * msk);
      int rb = (c >> 2) * 48 + (i >> 3);
      int r = (i & 7) * 4 + (c & 3);
      AF2[((size_t)(rb * 4 + kkq) * 64 + hh * 32 + r) * 8 + e] = f2bf(accA[k] * msk);
    }
  } else if (b < NT + 64) {
    const int g = (b - NT) * 256 + tid;  // 0..16383
    const int l = g & 63, zt = (g >> 6) & 3, kk = g >> 8;
    const float* src = wout + (zt * 32 + (l & 31)) * 1024 + kk * 16 + (l >> 5) * 8;
    uint16_t* dst = W2 + (size_t)g * 8;
#pragma unroll
    for (int e2 = 0; e2 < 8; ++e2) dst[e2] = f2bf(src[e2]);
  } else {
    const int t = (b - NT - 64) * 256 + tid;  // 0..147455
    const int i = t / NT, j = t - i * NT;
    float acc = 0.f;
#pragma unroll 8
    for (int s2 = 0; s2 < NS; ++s2) acc += mask[s2 * NT + i] * mask[s2 * NT + j];
    invn[t] = 1.f / (acc + 1e-3f);
  }
}

// ---- main: per block 8x8 (i,j) pairs, 8 c-slabs of K=128, fused GEMM1+GEMM2
// LDS: O dbuf 2x16 KB + invn 256 B (static, 33 KB -> 2+ blocks/CU)
// waves: GEMM1 wave = jt (j0+jt, all 8 i); GEMM2 wave = (mp, zp); no K-split.
__global__ __launch_bounds__(512, 4) void k_main(
    const uint16_t* __restrict__ AF2, const uint16_t* __restrict__ BF,
    const uint16_t* __restrict__ W2, const float* __restrict__ b_out,
    const float* __restrict__ invn, float* __restrict__ out) {
  __shared__ __align__(16) char lds[2 * 16384 + 256];
  float* invLds = (float*)(lds + 32768);
  const int tid = threadIdx.x;
  const int wv = tid >> 6, l = tid & 63;
  const int lo5 = l & 31, hi = l >> 5;
  const int ib = blockIdx.x;                // i-tile 0..47
  const int i0 = blockIdx.x * 8, j0 = blockIdx.y * 8;
  const int jt = wv;                        // GEMM1 role
  const int mp = wv >> 2, zp = wv & 3;      // GEMM2 role

  // stage invn for this block's 64 pairs
  if (tid < 64) invLds[tid] = invn[(size_t)(i0 + (tid >> 3)) * NT + j0 + (tid & 7)];

  // preload BF fragments (reused by all 8 slabs; GEMM1's K is s, same every slab)
  bf16x8 bfr[4];
  {
    const uint16_t* p = BF + (size_t)(j0 + jt) * 4 * 512 + (size_t)l * 8;
#pragma unroll
    for (int kk = 0; kk < 4; ++kk) bfr[kk] = *(const bf16x8*)(p + kk * 512);
  }

  f32x16 acc2 = (f32x16){};

  // O layout: byte = p*256 + kl*2, p = i*8+j (i = lo5>>2 of AF2 col r), kl = cl*32 + d

  // slab 0 prologue
  {
    const uint16_t* Ap = AF2 + ((size_t)(0 * 48 + ib) * 4) * 512 + (size_t)l * 8;
    f32x16 acc1 = (f32x16){};
#pragma unroll
    for (int kk = 0; kk < 4; ++kk) {
      bf16x8 afr = *(const bf16x8*)(Ap + kk * 512);
      acc1 = MFMA(bfr[kk], afr, acc1, 0, 0, 0);
    }
    const int p = (lo5 >> 2) * 8 + jt;
    const int base = p * 256 + (lo5 & 3) * 64 + hi * 8;
#pragma unroll
    for (int g = 0; g < 4; ++g) {
      uint64_t v = (uint64_t)pack2(acc1[4 * g + 0], acc1[4 * g + 1]) |
                   ((uint64_t)pack2(acc1[4 * g + 2], acc1[4 * g + 3]) << 32);
      *(uint64_t*)(lds + swzO(base + g * 16)) = v;
    }
  }
  __syncthreads();

  const int p2base = (mp * 32 + lo5) * 256 + hi * 16;  // GEMM2 A-read base (pre-swizzle)

  for (int cbk = 1; cbk <= 8; ++cbk) {
    // ---- GEMM1 for slab cbk (skipped on last iteration)
    f32x16 acc1 = (f32x16){};
    if (cbk < 8) {
      const uint16_t* Ap = AF2 + ((size_t)(cbk * 48 + ib) * 4) * 512 + (size_t)l * 8;
#pragma unroll
      for (int kk = 0; kk < 4; ++kk) {
        bf16x8 afr = *(const bf16x8*)(Ap + kk * 512);
        acc1 = MFMA(bfr[kk], afr, acc1, 0, 0, 0);
      }
    }

    // ---- GEMM2 for slab cbk-1 from buf[(cbk-1)&1]
    {
      char* ldsO = lds + ((cbk - 1) & 1) * 16384;
      const uint16_t* Wp = W2 + ((size_t)(((cbk - 1) * 8) * 4 + zp) * 64 + l) * 8;
#pragma unroll
      for (int kx = 0; kx < 8; ++kx) {
        bf16x8 of = *(const bf16x8*)(ldsO + swzO(p2base + kx * 32));
        bf16x8 wf = *(const bf16x8*)(Wp + (size_t)kx * 4 * 512);
        acc2 = MFMA(of, wf, acc2, 0, 0, 0);
      }
    }

    // ---- write O slab cbk into buf[cbk&1]
    if (cbk < 8) {
      char* ldsO = lds + (cbk & 1) * 16384;
      const int p = (lo5 >> 2) * 8 + jt;
      const int base = p * 256 + (lo5 & 3) * 64 + hi * 8;
#pragma unroll
      for (int g = 0; g < 4; ++g) {
        uint64_t v = (uint64_t)pack2(acc1[4 * g + 0], acc1[4 * g + 1]) |
                     ((uint64_t)pack2(acc1[4 * g + 2], acc1[4 * g + 3]) << 32);
        *(uint64_t*)(ldsO + swzO(base + g * 16)) = v;
      }
      __syncthreads();
    }
  }

  // ---- epilogue: acc2 tile = [rows p = mp*32+..][cols z = zp*32+lo5]
  const int z = zp * 32 + lo5;
  const float bo = b_out[z];
#pragma unroll
  for (int e = 0; e < 16; ++e) {
    const int prow = mp * 32 + (e & 3) + 8 * (e >> 2) + 4 * hi;  // pair = i*8+j
    const size_t n = (size_t)(i0 + (prow >> 3)) * NT + j0 + (prow & 7);
    out[n * CZ + z] = (acc2[e] + bo) * invLds[prow];
  }
}

extern "C" void kernel_launch(void* const* d_in, const int* in_sizes, int n_in,
                              void* d_out, int out_size, void* d_ws, size_t ws_size,
                              hipStream_t stream) {
  const float* m    = (const float*)d_in[0];
  const float* mask = (const float*)d_in[1];
  const float* lnw  = (const float*)d_in[2];
  const float* lnb  = (const float*)d_in[3];
  const float* w1   = (const float*)d_in[4];
  const float* w2   = (const float*)d_in[5];
  const float* wout = (const float*)d_in[6];
  const float* bout = (const float*)d_in[7];
  float* out = (float*)d_out;

  char* ws = (char*)d_ws;
  uint16_t* AF2 = (uint16_t*)ws;                        // 1.5 MB
  uint16_t* BF  = (uint16_t*)(ws + 1572864);            // 1.5 MB
  uint16_t* W2  = (uint16_t*)(ws + 3145728);            // 256 KB
  float* invn   = (float*)(ws + 3407872);               // 576 KB

  k_pre<<<1024, 256, 0, stream>>>(m, mask, lnw, lnb, w1, w2, wout, AF2, BF, W2, invn);
  k_main<<<dim3(NT / 8, NT / 8), 512, 0, stream>>>(AF2, BF, W2, bout, invn, out);
}